// Round 4
// baseline (190.407 us; speedup 1.0000x reference)
//
#include <hip/hip_runtime.h>
#include <math.h>
#include <limits.h>

#define NEG_INF -1e9f

// K1: s[e] = dot(edge_emb[e], W) -- one wave (64 lanes) per 256-float row.
// Memory-floor kernel: reads emb exactly once (102.4 MB), coalesced float4,
// runs at ~82% of HBM peak. Also zeroes the ticket counter for K2
// (workspace is re-poisoned every iteration).
__global__ __launch_bounds__(256) void k_edge_dot(
    const float* __restrict__ emb, const float* __restrict__ W,
    float* __restrict__ s, int* __restrict__ counter, int n_edges)
{
    if (blockIdx.x == 0 && threadIdx.x == 0) *counter = 0;
    int wave = (blockIdx.x * (int)blockDim.x + (int)threadIdx.x) >> 6;
    int lane = threadIdx.x & 63;
    if (wave >= n_edges) return;
    const float4 e = ((const float4*)emb)[(size_t)wave * 64 + lane];
    const float4 w = ((const float4*)W)[lane];
    float d = e.x * w.x + e.y * w.y + e.z * w.z + e.w * w.w;
#pragma unroll
    for (int off = 32; off; off >>= 1) d += __shfl_down(d, off, 64);
    if (lane == 0) s[wave] = d;
}

// K2 (slot-parallel, max_len == 16): one thread per (path, slot).
// 320K threads over 1250 blocks of 256 -> all 256 CUs busy, ~20 waves/CU,
// each wave issues exactly ONE divergent gather (vs 16 serialized before).
// Then: 16-lane segmented sum -> 16 block logits -> per-block softmax
// partials -> last block (device-scope ticket) computes p, logprob, z[p].
__global__ __launch_bounds__(256) void k_fused_slot(
    const float* __restrict__ s, const int* __restrict__ paths,
    const int* __restrict__ path_lens, const int* __restrict__ path_mask,
    const float* __restrict__ b, const float* __restrict__ emb,
    float* __restrict__ pmax, int* __restrict__ pidx, float* __restrict__ psum,
    int* __restrict__ counter, float* __restrict__ out,
    int n_paths, int max_len)
{
    __shared__ float bl[16];  __shared__ int bix[16];
    __shared__ float rv[4];   __shared__ int ri[4];   __shared__ float rs[4];
    __shared__ float s_M, s_S; __shared__ int s_P, s_last;

    const int tid = threadIdx.x, lane = tid & 63, wv = tid >> 6;
    const int t = blockIdx.x * 256 + tid;          // global (path,slot) id
    const int p = t >> 4, slot = t & 15;

    // ---- gather + 16-lane segmented sum (coalesced path load, 1 gather) ----
    float val = 0.f; int mask = 0, len = 1;
    const int inb = (p < n_paths);
    if (inb) {
        mask = path_mask[p];                        // 16-lane broadcast load
        len  = path_lens[p] + 1;                    // 1..16
        if (mask && slot < len) val = s[paths[t]];  // exec-masked gather
    }
#pragma unroll
    for (int m = 1; m <= 8; m <<= 1) val += __shfl_xor(val, m, 16);
    if (slot == 0) {                                // 16 lanes per block
        bl[tid >> 4]  = inb ? (mask ? val / (float)len + b[0] : NEG_INF)
                            : -INFINITY;
        bix[tid >> 4] = inb ? p : INT_MAX;
    }
    __syncthreads();

    // ---- block partial (serial over 16 logits: ~trivial) + ticket ----
    if (tid == 0) {
        float bm = -INFINITY; int bi = INT_MAX;
        for (int i = 0; i < 16; ++i)
            if (bl[i] > bm || (bl[i] == bm && bix[i] < bi)) { bm = bl[i]; bi = bix[i]; }
        float bs = 0.f;
        if (bi != INT_MAX)
            for (int i = 0; i < 16; ++i)
                if (bix[i] != INT_MAX) bs += expf(bl[i] - bm);
        pmax[blockIdx.x] = bm;
        pidx[blockIdx.x] = bi;
        psum[blockIdx.x] = bs;
        __threadfence();                            // release partials
        int tk = atomicAdd(counter, 1);             // device-scope ticket
        s_last = (tk == (int)gridDim.x - 1) ? 1 : 0;
    }
    __syncthreads();
    if (!s_last) return;
    __threadfence();                                // acquire all partials

    // ---- combine: global max + first-index argmax over nb partials ----
    const int nb = gridDim.x;
    float mv = -INFINITY; int mi = INT_MAX;
    for (int i = tid; i < nb; i += 256) {
        float tv = pmax[i]; int ti = pidx[i];
        if (tv > mv || (tv == mv && ti < mi)) { mv = tv; mi = ti; }
    }
#pragma unroll
    for (int off = 32; off; off >>= 1) {
        float ov = __shfl_down(mv, off, 64);
        int   oi = __shfl_down(mi, off, 64);
        if (ov > mv || (ov == mv && oi < mi)) { mv = ov; mi = oi; }
    }
    if (lane == 0) { rv[wv] = mv; ri[wv] = mi; }
    __syncthreads();
    if (tid == 0) {
        float M = rv[0]; int P = ri[0];
        for (int w = 1; w < 4; ++w)
            if (rv[w] > M || (rv[w] == M && ri[w] < P)) { M = rv[w]; P = ri[w]; }
        s_M = M; s_P = P;
    }
    __syncthreads();
    const float M = s_M; const int P = s_P;

    // ---- S = sum_b psum[b] * exp(pmax[b] - M); empty blocks contribute 0 ----
    float sp = 0.f;
    for (int i = tid; i < nb; i += 256)
        sp += psum[i] * expf(pmax[i] - M);
#pragma unroll
    for (int off = 32; off; off >>= 1) sp += __shfl_down(sp, off, 64);
    if (lane == 0) rs[wv] = sp;
    __syncthreads();
    if (tid == 0) s_S = rs[0] + rs[1] + rs[2] + rs[3];
    __syncthreads();

    // ---- z[P]: 256 threads, one per hidden dim, in-order edge sum ----
    const int lenP = path_lens[P] + 1;
    const int* pp = paths + (size_t)P * max_len;
    float acc = 0.f;
    for (int j = 0; j < lenP; ++j)
        acc += emb[(size_t)pp[j] * 256 + tid];
    out[2 + tid] = acc / (float)lenP;
    if (tid == 0) { out[0] = (float)P; out[1] = -logf(s_S); }  // l_P == M exactly
}

// ==================== generic fallback (round-1 structure, proven) ====================

__global__ __launch_bounds__(256) void k_fused_gen(
    const float* __restrict__ s, const int* __restrict__ paths,
    const int* __restrict__ path_lens, const int* __restrict__ path_mask,
    const float* __restrict__ b, const float* __restrict__ emb,
    float* __restrict__ pmax, int* __restrict__ pidx, float* __restrict__ psum,
    int* __restrict__ counter, float* __restrict__ out,
    int n_paths, int max_len)
{
    __shared__ float rv[4]; __shared__ int ri[4]; __shared__ float rs[4];
    __shared__ float s_M, s_S; __shared__ int s_P, s_last;

    const int tid = threadIdx.x, lane = tid & 63, wv = tid >> 6;
    const int p = blockIdx.x * 256 + tid;

    float v = -INFINITY; int vi = INT_MAX;
    if (p < n_paths) {
        vi = p;
        if (path_mask[p] == 0) v = NEG_INF;
        else {
            int len = path_lens[p] + 1;
            const int* pp = paths + (size_t)p * max_len;
            float acc = 0.f;
            for (int j = 0; j < len; ++j) acc += s[pp[j]];
            v = acc / (float)len + b[0];
        }
    }
    float bv = v; int bi = vi;
#pragma unroll
    for (int off = 32; off; off >>= 1) {
        float ov = __shfl_down(bv, off, 64);
        int   oi = __shfl_down(bi, off, 64);
        if (ov > bv || (ov == bv && oi < bi)) { bv = ov; bi = oi; }
    }
    if (lane == 0) { rv[wv] = bv; ri[wv] = bi; }
    __syncthreads();
    if (tid == 0) {
        float mvv = rv[0]; int mii = ri[0];
        for (int w = 1; w < 4; ++w)
            if (rv[w] > mvv || (rv[w] == mvv && ri[w] < mii)) { mvv = rv[w]; mii = ri[w]; }
        s_M = mvv; s_P = mii;
    }
    __syncthreads();
    const float bm = s_M;
    float se = expf(v - bm);
#pragma unroll
    for (int off = 32; off; off >>= 1) se += __shfl_down(se, off, 64);
    if (lane == 0) rs[wv] = se;
    __syncthreads();
    if (tid == 0) {
        pmax[blockIdx.x] = bm;
        pidx[blockIdx.x] = s_P;
        psum[blockIdx.x] = rs[0] + rs[1] + rs[2] + rs[3];
        __threadfence();
        int tk = atomicAdd(counter, 1);
        s_last = (tk == (int)gridDim.x - 1) ? 1 : 0;
    }
    __syncthreads();
    if (!s_last) return;
    __threadfence();

    const int nb = gridDim.x;
    float mv = -INFINITY; int mi = INT_MAX;
    for (int i = tid; i < nb; i += 256) {
        float tv = pmax[i]; int ti = pidx[i];
        if (tv > mv || (tv == mv && ti < mi)) { mv = tv; mi = ti; }
    }
#pragma unroll
    for (int off = 32; off; off >>= 1) {
        float ov = __shfl_down(mv, off, 64);
        int   oi = __shfl_down(mi, off, 64);
        if (ov > mv || (ov == mv && oi < mi)) { mv = ov; mi = oi; }
    }
    if (lane == 0) { rv[wv] = mv; ri[wv] = mi; }
    __syncthreads();
    if (tid == 0) {
        float M = rv[0]; int P = ri[0];
        for (int w = 1; w < 4; ++w)
            if (rv[w] > M || (rv[w] == M && ri[w] < P)) { M = rv[w]; P = ri[w]; }
        s_M = M; s_P = P;
    }
    __syncthreads();
    const float M = s_M; const int P = s_P;
    float sp = 0.f;
    for (int i = tid; i < nb; i += 256)
        sp += psum[i] * expf(pmax[i] - M);
#pragma unroll
    for (int off = 32; off; off >>= 1) sp += __shfl_down(sp, off, 64);
    if (lane == 0) rs[wv] = sp;
    __syncthreads();
    if (tid == 0) s_S = rs[0] + rs[1] + rs[2] + rs[3];
    __syncthreads();

    const int lenP = path_lens[P] + 1;
    const int* pp = paths + (size_t)P * max_len;
    if (tid < 256) {
        float acc = 0.f;
        for (int j = 0; j < lenP; ++j)
            acc += emb[(size_t)pp[j] * 256 + tid];
        out[2 + tid] = acc / (float)lenP;
    }
    if (tid == 0) { out[0] = (float)P; out[1] = -logf(s_S); }
}

// ==================== launcher ====================

extern "C" void kernel_launch(void* const* d_in, const int* in_sizes, int n_in,
                              void* d_out, int out_size, void* d_ws, size_t ws_size,
                              hipStream_t stream) {
    const float* emb       = (const float*)d_in[0];   // [n_edges, 256]
    const int*   paths     = (const int*)  d_in[1];   // [n_paths, max_len]
    const int*   path_lens = (const int*)  d_in[2];   // [n_paths]
    const int*   path_mask = (const int*)  d_in[3];   // [n_paths]
    const float* W         = (const float*)d_in[4];   // [256]
    const float* b         = (const float*)d_in[5];   // [1]

    int hidden  = in_sizes[4];                 // 256
    int n_edges = in_sizes[0] / hidden;        // 100000
    int n_paths = in_sizes[2];                 // 20000
    int max_len = in_sizes[1] / n_paths;       // 16

    // workspace layout (sized for the larger of the two paths)
    float* s = (float*)d_ws;                   // [n_edges]

    // K1: one wave per edge row -> 4 waves/block (also zeroes counter)
    if (max_len == 16 && hidden == 256) {
        int nb2 = (n_paths * 16 + 255) / 256;  // 1250 blocks, 16 paths each
        float* pmax    = s + n_edges;          // [nb2]
        float* psum    = pmax + nb2;           // [nb2]
        int*   pidx    = (int*)(psum + nb2);   // [nb2]
        int*   counter = pidx + nb2;           // [1]

        int blocks1 = (n_edges * 64 + 255) / 256;
        k_edge_dot<<<blocks1, 256, 0, stream>>>(emb, W, s, counter, n_edges);
        k_fused_slot<<<nb2, 256, 0, stream>>>(s, paths, path_lens, path_mask,
                                              b, emb, pmax, pidx, psum, counter,
                                              (float*)d_out, n_paths, max_len);
    } else {
        int blocks2 = (n_paths + 255) / 256;
        float* pmax    = s + n_edges;
        float* psum    = pmax + blocks2;
        int*   pidx    = (int*)(psum + blocks2);
        int*   counter = pidx + blocks2;

        int blocks1 = (n_edges * 64 + 255) / 256;
        k_edge_dot<<<blocks1, 256, 0, stream>>>(emb, W, s, counter, n_edges);
        k_fused_gen<<<blocks2, 256, 0, stream>>>(s, paths, path_lens, path_mask,
                                                 b, emb, pmax, pidx, psum, counter,
                                                 (float*)d_out, n_paths, max_len);
    }
}